// Round 10
// baseline (413.834 us; speedup 1.0000x reference)
//
#include <hip/hip_runtime.h>
#include <hip/hip_bf16.h>

// Model_39676907885326: out = softmax(causal(q)) @ e
//   e[i,j,l]  = sum_k in[i,j,k] * w[l,k,j]
//   attn[i,j,l] = softmax_{l<=j}( (sum_k in[i,j,k]) * w[i,j,l] / (0.5 + sum_l w[i,j,l]) )
//   out[i]    = attn[i] @ e[i]
//
// Pipeline (ws regions, bytes):
//   R0 [0, N3) bf16          : wt[j][l][k]        (kT out, k_e2 in)
//   R1 [N3, 2*N3) bf16       : e[i][j=m][l]       (k_e2 out, k_av in)
//   R2 [2*N3, 3*N3) bf16     : attn[i][j][m]      (k_attn out, k_av in)
//   RS [3*N3 ..) fp32 N2     : rs[i][j]           (k_e2 out, k_attn in)
//   kT -> k_e2(+rs) -> k_attn(rs) -> k_av128t
//
// R10: k_eT pass ELIMINATED. k_av128t stages B directly from e[i][m][l] with
// an in-LDS transpose: 4x16B row loads -> b64 packs -> [l][m] tile with 144B
// row stride (bank-rotating pad, 16B-aligned) + XOR m-chunk swizzle. Fragment
// reads identical to r9. Saves 36 us pass + 226 MB HBM round-trip.

#define N 384
#define N2 (N * N)
#define BK 64
static const size_t N3 = (size_t)N * N * N;

typedef __attribute__((ext_vector_type(8))) short s16x8;
typedef __attribute__((ext_vector_type(4))) float f32x4;

#define AS1 __attribute__((address_space(1)))
#define AS3 __attribute__((address_space(3)))
__device__ __forceinline__ void gll16(const void* g, void* l) {
    __builtin_amdgcn_global_load_lds((const AS1 unsigned int*)g,
                                     (AS3 unsigned int*)l, 16, 0, 0);
}

__device__ __forceinline__ unsigned short f32_to_bf16(float f) {
    unsigned int u = __float_as_uint(f);
    u += 0x7FFFu + ((u >> 16) & 1u);
    return (unsigned short)(u >> 16);
}
__device__ __forceinline__ unsigned int pk2(float a, float b) {
    return (unsigned int)f32_to_bf16(a) | ((unsigned int)f32_to_bf16(b) << 16);
}

// ---------------------------------------------------------------------------
// kT: wt[j*N2 + r] = bf16(w[r*N + j]), r = l*N+k
// ---------------------------------------------------------------------------
__global__ __launch_bounds__(256) void kT(const float* __restrict__ w,
                                          unsigned short* __restrict__ wt) {
    __shared__ unsigned short tile[64][68];
    const int r0 = blockIdx.x * 64;
    const int j0 = blockIdx.y * 64;
    const int tx = threadIdx.x & 63;
    const int ty = threadIdx.x >> 6;
#pragma unroll
    for (int p = 0; p < 16; ++p) {
        const int r = ty * 16 + p;
        tile[r][tx] = f32_to_bf16(w[(size_t)(r0 + r) * N + j0 + tx]);
    }
    __syncthreads();
#pragma unroll
    for (int p = 0; p < 16; ++p) {
        const int jj = ty * 16 + p;
        wt[(size_t)(j0 + jj) * N2 + r0 + tx] = tile[tx][jj];
    }
}

// ---------------------------------------------------------------------------
// k_e2: per j: e[i0..i0+63, j, l0..l0+191] = in[i,j,:] . wt[j][l][:]
// (r5 structure, unchanged)
// ---------------------------------------------------------------------------
__global__ __launch_bounds__(256, 4) void k_e2(const float* __restrict__ in,
                                               const unsigned short* __restrict__ wt,
                                               unsigned short* __restrict__ e,
                                               float* __restrict__ rs) {
    __shared__ union {
        struct { unsigned short A[64 * 64]; unsigned short B[192 * 64]; } s;
        unsigned short C[64 * 200];
    } sm;

    const int lin = blockIdx.x;               // 4608 = 8 * 576
    const int swz = (lin & 7) * 576 + (lin >> 3);
    const int j   = swz / 12;
    const int sub = swz % 12;
    const int i0  = (sub >> 1) * 64;
    const int l0  = (sub & 1) * 192;

    const int t = threadIdx.x, lane = t & 63, wv = t >> 6;
    const int fr = lane & 15, fx = lane >> 4;

    const int ra = t >> 2, ca = (t & 3) * 2;
    const float* Ab = in + (size_t)(i0 + ra) * N2 + (size_t)j * N + ca * 8;
    unsigned short* AsW0 = sm.s.A + ra * 64 + (((ca + 0) ^ (ra & 7)) * 8);
    unsigned short* AsW1 = sm.s.A + ra * 64 + (((ca + 1) ^ (ra & 7)) * 8);

    const unsigned short* Wj = wt + (size_t)j * N2 + (size_t)l0 * N;
    const int rb_off = lane >> 3;
    const int p8     = lane & 7;

    f32x4 acc[4][3];
#pragma unroll
    for (int m = 0; m < 4; ++m)
#pragma unroll
        for (int n = 0; n < 3; ++n) acc[m][n] = (f32x4){0.f, 0.f, 0.f, 0.f};

    float rsum = 0.f;

    float4 va[4];
    va[0] = *(const float4*)(Ab);
    va[1] = *(const float4*)(Ab + 4);
    va[2] = *(const float4*)(Ab + 8);
    va[3] = *(const float4*)(Ab + 12);

    for (int k0 = 0; k0 < N; k0 += BK) {
        __syncthreads();
        {
            rsum += (va[0].x + va[0].y + va[0].z + va[0].w) +
                    (va[1].x + va[1].y + va[1].z + va[1].w) +
                    (va[2].x + va[2].y + va[2].z + va[2].w) +
                    (va[3].x + va[3].y + va[3].z + va[3].w);
            uint4 a0, a1;
            a0.x = pk2(va[0].x, va[0].y); a0.y = pk2(va[0].z, va[0].w);
            a0.z = pk2(va[1].x, va[1].y); a0.w = pk2(va[1].z, va[1].w);
            a1.x = pk2(va[2].x, va[2].y); a1.y = pk2(va[2].z, va[2].w);
            a1.z = pk2(va[3].x, va[3].y); a1.w = pk2(va[3].z, va[3].w);
            *(uint4*)AsW0 = a0;
            *(uint4*)AsW1 = a1;
        }
#pragma unroll
        for (int itb = 0; itb < 6; ++itb) {
            const int rb = wv * 48 + itb * 8 + rb_off;
            const int sc = p8 ^ (rb & 7);
            gll16(Wj + (size_t)rb * N + k0 + sc * 8,
                  sm.s.B + (wv * 48 + itb * 8) * 64);
        }
        if (k0 + BK < N) {
            const float* An = Ab + k0 + BK;
            va[0] = *(const float4*)(An);
            va[1] = *(const float4*)(An + 4);
            va[2] = *(const float4*)(An + 8);
            va[3] = *(const float4*)(An + 12);
        }
        __syncthreads();
#pragma unroll
        for (int kk = 0; kk < 2; ++kk) {
            s16x8 af[4], bf[3];
#pragma unroll
            for (int m = 0; m < 4; ++m) {
                const int row = m * 16 + fr;
                const int x   = (kk * 4 + fx) ^ (row & 7);
                af[m] = *(const s16x8*)(sm.s.A + row * 64 + x * 8);
            }
#pragma unroll
            for (int n = 0; n < 3; ++n) {
                const int row = wv * 48 + n * 16 + fr;
                const int x   = (kk * 4 + fx) ^ (row & 7);
                bf[n] = *(const s16x8*)(sm.s.B + row * 64 + x * 8);
            }
#pragma unroll
            for (int m = 0; m < 4; ++m)
#pragma unroll
                for (int n = 0; n < 3; ++n)
                    acc[m][n] = __builtin_amdgcn_mfma_f32_16x16x32_bf16(
                        af[m], bf[n], acc[m][n], 0, 0, 0);
        }
    }

    rsum += __shfl_xor(rsum, 1, 64);
    rsum += __shfl_xor(rsum, 2, 64);
    if (rs != nullptr && l0 == 0 && (t & 3) == 0)
        rs[(size_t)(i0 + ra) * N + j] = rsum;

    __syncthreads();
#pragma unroll
    for (int m = 0; m < 4; ++m)
#pragma unroll
        for (int n = 0; n < 3; ++n)
#pragma unroll
            for (int r = 0; r < 4; ++r)
                sm.C[(m * 16 + fx * 4 + r) * 200 + wv * 48 + n * 16 + fr] =
                    f32_to_bf16(acc[m][n][r]);
    __syncthreads();
#pragma unroll
    for (int it = 0; it < 6; ++it) {
        const int cid = it * 256 + t;
        const int row = cid / 24;
        const int c   = cid % 24;
        *(uint4*)(e + (size_t)(i0 + row) * N2 + (size_t)j * N + l0 + c * 8) =
            *(const uint4*)&sm.C[row * 200 + c * 8];
    }
}

// ---------------------------------------------------------------------------
// k_attn: one wave per row (i,j); rs precomputed by k_e2
// ---------------------------------------------------------------------------
template <bool HAVE_RS>
__global__ __launch_bounds__(256) void k_attn(const float* __restrict__ in,
                                              const float* __restrict__ w,
                                              const float* __restrict__ rs,
                                              unsigned short* __restrict__ attn) {
    const int row  = blockIdx.x * 4 + (threadIdx.x >> 6);
    const int lane = threadIdx.x & 63;
    const int jr   = row % N;

    const float2* wp = (const float2*)(w + (size_t)row * N);

    float2 wv[3];
    float rs_in = 0.f, rs_w = 0.f;
#pragma unroll
    for (int c = 0; c < 3; ++c) {
        wv[c] = wp[lane + 64 * c];
        rs_w += wv[c].x + wv[c].y;
    }
    if (HAVE_RS) {
#pragma unroll
        for (int s = 1; s < 64; s <<= 1) rs_w += __shfl_xor(rs_w, s, 64);
        rs_in = rs[row];
    } else {
        const float2* ip = (const float2*)(in + (size_t)row * N);
#pragma unroll
        for (int c = 0; c < 3; ++c) {
            float2 iv = ip[lane + 64 * c];
            rs_in += iv.x + iv.y;
        }
#pragma unroll
        for (int s = 1; s < 64; s <<= 1) {
            rs_in += __shfl_xor(rs_in, s, 64);
            rs_w  += __shfl_xor(rs_w, s, 64);
        }
    }
    const float scale = rs_in / (0.5f + rs_w);

    float2 q[3];
    float mx = -INFINITY;
#pragma unroll
    for (int c = 0; c < 3; ++c) {
        const int l = (lane + 64 * c) * 2;
        q[c].x = (l     <= jr) ? scale * wv[c].x : -INFINITY;
        q[c].y = (l + 1 <= jr) ? scale * wv[c].y : -INFINITY;
        mx = fmaxf(mx, fmaxf(q[c].x, q[c].y));
    }
#pragma unroll
    for (int s = 1; s < 64; s <<= 1) mx = fmaxf(mx, __shfl_xor(mx, s, 64));

    float2 p[3];
    float sum = 0.f;
#pragma unroll
    for (int c = 0; c < 3; ++c) {
        const int l = (lane + 64 * c) * 2;
        p[c].x = (l     <= jr) ? exp2f((q[c].x - mx) * 1.44269504f) : 0.f;
        p[c].y = (l + 1 <= jr) ? exp2f((q[c].y - mx) * 1.44269504f) : 0.f;
        sum += p[c].x + p[c].y;
    }
#pragma unroll
    for (int s = 1; s < 64; s <<= 1) sum += __shfl_xor(sum, s, 64);
    const float inv = 1.f / sum;
    unsigned int* ap = (unsigned int*)(attn + (size_t)row * N);
#pragma unroll
    for (int c = 0; c < 3; ++c)
        ap[lane + 64 * c] = pk2(p[c].x * inv, p[c].y * inv);
}

// ---------------------------------------------------------------------------
// k_av128t: per i: out[j0..j0+127, l0..l0+127] = attn[i] @ e[i]  (K = m)
// A (attn, [j][m]) staged via gll (linear, pre-swizzled source).
// B (e, [m][l]) staged TRANSPOSED into LDS [l][m] (stride 72 elems = 144B):
// 4 x 16B row loads per thread -> per-l b64 packs of 4 m's -> ds_write_b64.
// Fragment reads identical to r9's et path. Triangular K: nt = j0/64 + 2.
// ---------------------------------------------------------------------------
__global__ __launch_bounds__(256, 4) void k_av128t(const unsigned short* __restrict__ attn,
                                                   const unsigned short* __restrict__ e,
                                                   float* __restrict__ out) {
    __shared__ union {
        struct { unsigned short A[128 * 64]; unsigned short B[128 * 72]; } s;
        float C[32 * 132];
    } sm;

    const int lin = blockIdx.x;               // 3456 = 8 * 432
    const int swz = (lin & 7) * 432 + (lin >> 3);
    const int i   = swz / 9;
    const int sub = swz % 9;
    const int j0  = (sub / 3) * 128;
    const int l0  = (sub % 3) * 128;
    const int nt  = (j0 >> 6) + 2;            // K tiles: 2 / 4 / 6

    const int t = threadIdx.x, lane = t & 63, wv = t >> 6;
    const int fr = lane & 15, fx = lane >> 4;
    const int wr = (wv >> 1) * 64;            // j-offset of wave tile
    const int wc = (wv & 1) * 64;             // l-offset of wave tile
    const int rb_off = lane >> 3;
    const int p8     = lane & 7;

    // B transpose-staging thread mapping: m-group (4 rows) + l-chunk (8 cols)
    const int mg  = t & 15;                   // m-group: rows mg*4 .. mg*4+3
    const int lcg = t >> 4;                   // l-chunk 0..15
    const int bx  = (mg >> 1);                // m-chunk (8 m) index 0..7
    const int bh  = (mg & 1) * 4;             // half-chunk elem offset

    const unsigned short* Ag = attn + (size_t)i * N2 + (size_t)j0 * N;
    const unsigned short* Eg = e + (size_t)i * N2 + l0 + lcg * 8;

    f32x4 acc[4][4];
#pragma unroll
    for (int m = 0; m < 4; ++m)
#pragma unroll
        for (int n = 0; n < 4; ++n) acc[m][n] = (f32x4){0.f, 0.f, 0.f, 0.f};

    for (int tt = 0; tt < nt; ++tt) {
        const int k0 = tt * 64;               // m0 of this K-step
        __syncthreads();
        // A: 128 attn rows via gll (linear dest, pre-swizzled source)
#pragma unroll
        for (int op = 0; op < 4; ++op) {
            const int rr = wv * 32 + op * 8 + rb_off;
            const int sc = p8 ^ (rr & 7);
            gll16(Ag + (size_t)rr * N + k0 + sc * 8,
                  sm.s.A + (wv * 32 + op * 8) * 64);
        }
        // B: load 4 m-rows x 8 l's, pack per-l quads, transposed ds_write_b64
        {
            uint4 bv0 = *(const uint4*)(Eg + (size_t)(k0 + mg * 4 + 0) * N);
            uint4 bv1 = *(const uint4*)(Eg + (size_t)(k0 + mg * 4 + 1) * N);
            uint4 bv2 = *(const uint4*)(Eg + (size_t)(k0 + mg * 4 + 2) * N);
            uint4 bv3 = *(const uint4*)(Eg + (size_t)(k0 + mg * 4 + 3) * N);
            const unsigned short* p0 = (const unsigned short*)&bv0;
            const unsigned short* p1 = (const unsigned short*)&bv1;
            const unsigned short* p2 = (const unsigned short*)&bv2;
            const unsigned short* p3 = (const unsigned short*)&bv3;
#pragma unroll
            for (int q = 0; q < 8; ++q) {
                const int l = lcg * 8 + q;
                uint2 v;
                v.x = (unsigned int)p0[q] | ((unsigned int)p1[q] << 16);
                v.y = (unsigned int)p2[q] | ((unsigned int)p3[q] << 16);
                *(uint2*)(sm.s.B + l * 72 + ((bx ^ (l & 7)) * 8) + bh) = v;
            }
        }
        __syncthreads();
#pragma unroll
        for (int kk = 0; kk < 2; ++kk) {
            s16x8 af[4], bf[4];
#pragma unroll
            for (int m = 0; m < 4; ++m) {
                const int row = wr + m * 16 + fr;
                const int x   = (kk * 4 + fx) ^ (row & 7);
                af[m] = *(const s16x8*)(sm.s.A + row * 64 + x * 8);
            }
#pragma unroll
            for (int n = 0; n < 4; ++n) {
                const int row = wc + n * 16 + fr;     // l-row
                const int x   = (kk * 4 + fx) ^ (row & 7);
                bf[n] = *(const s16x8*)(sm.s.B + row * 72 + x * 8);
            }
#pragma unroll
            for (int m = 0; m < 4; ++m)
#pragma unroll
                for (int n = 0; n < 4; ++n)
                    acc[m][n] = __builtin_amdgcn_mfma_f32_16x16x32_bf16(
                        af[m], bf[n], acc[m][n], 0, 0, 0);
        }
    }

    // epilogue: 4 phases of 32 fp32 rows [p*32, p*32+32)
    const int rq = fx * 4;
#pragma unroll
    for (int p = 0; p < 4; ++p) {
        __syncthreads();
        if ((wv >> 1) == (p >> 1)) {
            const int mbase = (p & 1) * 2;
#pragma unroll
            for (int mm = 0; mm < 2; ++mm)
#pragma unroll
                for (int n = 0; n < 4; ++n)
#pragma unroll
                    for (int r = 0; r < 4; ++r)
                        sm.C[(mm * 16 + rq + r) * 132 + wc + n * 16 + fr] =
                            acc[mbase + mm][n][r];
        }
        __syncthreads();
#pragma unroll
        for (int it = 0; it < 4; ++it) {
            const int cid = it * 256 + t;
            const int row = cid >> 5;
            const int c   = cid & 31;
            *(float4*)(out + (size_t)i * N2 + (size_t)(j0 + p * 32 + row) * N + l0 + c * 4) =
                *(const float4*)&sm.C[row * 132 + c * 4];
        }
    }
}

extern "C" void kernel_launch(void* const* d_in, const int* in_sizes, int n_in,
                              void* d_out, int out_size, void* d_ws, size_t ws_size,
                              hipStream_t stream) {
    const float* in = (const float*)d_in[0];
    const float* w  = (const float*)d_in[1];
    float* out      = (float*)d_out;

    unsigned short* r0   = (unsigned short*)d_ws;            // wt
    unsigned short* r1   = (unsigned short*)d_ws + N3;       // e
    unsigned short* attn = (unsigned short*)d_ws + 2 * N3;   // attn
    const bool have_rs = ws_size >= 3 * N3 * sizeof(unsigned short) + (size_t)N2 * sizeof(float);
    float* rs = have_rs ? (float*)((unsigned short*)d_ws + 3 * N3) : nullptr;

    kT<<<dim3(N2 / 64, N / 64), 256, 0, stream>>>(w, r0);
    k_e2<<<dim3(4608), 256, 0, stream>>>(in, r0, r1, rs);
    if (have_rs)
        k_attn<true><<<dim3(N2 / 4), 256, 0, stream>>>(in, w, rs, attn);
    else
        k_attn<false><<<dim3(N2 / 4), 256, 0, stream>>>(in, w, nullptr, attn);
    k_av128t<<<dim3(3456), 256, 0, stream>>>(attn, r1, out);
}

// Round 11
// 393.658 us; speedup vs baseline: 1.0513x; 1.0513x over previous
//
#include <hip/hip_runtime.h>
#include <hip/hip_bf16.h>

// Model_39676907885326: out = softmax(causal(q)) @ e
//   e[i,j,l]  = sum_k in[i,j,k] * w[l,k,j]
//   attn[i,j,l] = softmax_{l<=j}( (sum_k in[i,j,k]) * w[i,j,l] / (0.5 + sum_l w[i,j,l]) )
//   out[i]    = attn[i] @ e[i]
//
// Pipeline (ws regions):
//   R0 [0, N3) bf16        : wt[j][l][k]  ->  et[i][l][m]
//   R1 [N3, 2*N3) bf16     : e[i][j][l]   ->  attn[i][j][m]
//   RS [2*N3 ..) fp32 N2   : rs[i][j]
//   kT -> k_e3(+rs) -> k_eT -> k_attn(rs) -> k_av3
//
// R11: counted-vmcnt B-dbuf pipeline at UNCHANGED occupancy (r6's mistake was
// paying 64KB LDS). BM=64, BN=128, BK=64: A single-buffer (reg-staged) 8KB +
// B double-buffer 32KB = 40KB -> 4 blocks/CU. Per step: stage A | issue
// B(t+1) glls | prefetch A(t+1) regs | lgkm+BAR | MFMA | vmcnt(counted) | BAR.
// B latency spans the MFMA phase (T3/T4); never vmcnt(0) in the loop.

#define N 384
#define N2 (N * N)
#define BK 64
static const size_t N3 = (size_t)N * N * N;

typedef __attribute__((ext_vector_type(8))) short s16x8;
typedef __attribute__((ext_vector_type(4))) float f32x4;

#define AS1 __attribute__((address_space(1)))
#define AS3 __attribute__((address_space(3)))
__device__ __forceinline__ void gll16(const void* g, void* l) {
    __builtin_amdgcn_global_load_lds((const AS1 unsigned int*)g,
                                     (AS3 unsigned int*)l, 16, 0, 0);
}
#define WAITL0 asm volatile("s_waitcnt lgkmcnt(0)" ::: "memory")
#define BAR    __builtin_amdgcn_s_barrier()

__device__ __forceinline__ unsigned short f32_to_bf16(float f) {
    unsigned int u = __float_as_uint(f);
    u += 0x7FFFu + ((u >> 16) & 1u);
    return (unsigned short)(u >> 16);
}
__device__ __forceinline__ unsigned int pk2(float a, float b) {
    return (unsigned int)f32_to_bf16(a) | ((unsigned int)f32_to_bf16(b) << 16);
}

// ---------------------------------------------------------------------------
// kT: wt[j*N2 + r] = bf16(w[r*N + j]), r = l*N+k
// ---------------------------------------------------------------------------
__global__ __launch_bounds__(256) void kT(const float* __restrict__ w,
                                          unsigned short* __restrict__ wt) {
    __shared__ unsigned short tile[64][68];
    const int r0 = blockIdx.x * 64;
    const int j0 = blockIdx.y * 64;
    const int tx = threadIdx.x & 63;
    const int ty = threadIdx.x >> 6;
#pragma unroll
    for (int p = 0; p < 16; ++p) {
        const int r = ty * 16 + p;
        tile[r][tx] = f32_to_bf16(w[(size_t)(r0 + r) * N + j0 + tx]);
    }
    __syncthreads();
#pragma unroll
    for (int p = 0; p < 16; ++p) {
        const int jj = ty * 16 + p;
        wt[(size_t)(j0 + jj) * N2 + r0 + tx] = tile[tx][jj];
    }
}

// ---------------------------------------------------------------------------
// k_e3: per j: e[i0..i0+63, j, l0..l0+127] = in[i,j,:] . wt[j][l][:]
// BM=64, BN=128. A reg-staged (+fused rsum); B gll double-buffered with
// counted vmcnt(4) so B(t+1) latency hides under MFMA(t).
// ---------------------------------------------------------------------------
__global__ __launch_bounds__(256, 4) void k_e3(const float* __restrict__ in,
                                               const unsigned short* __restrict__ wt,
                                               unsigned short* __restrict__ e,
                                               float* __restrict__ rs) {
    __shared__ union {
        struct { unsigned short A[64 * 64]; unsigned short B[2][128 * 64]; } s; // 40960 B
        unsigned short C[64 * 136];
    } sm;

    const int lin = blockIdx.x;               // 6912 = 8 * 864
    const int swz = (lin & 7) * 864 + (lin >> 3);
    const int j   = swz / 18;
    const int sub = swz % 18;
    const int i0  = (sub / 3) * 64;
    const int l0  = (sub % 3) * 128;

    const int t = threadIdx.x, lane = t & 63, wv = t >> 6;
    const int fr = lane & 15, fx = lane >> 4;
    const int wr = (wv >> 1) * 32;            // output row offset of wave
    const int wc = (wv & 1) * 64;             // output col offset of wave
    const int rb_off = lane >> 3;
    const int p8     = lane & 7;

    // A path (reg-staged): thread -> row ra, chunks ca, ca+1
    const int ra = t >> 2, ca = (t & 3) * 2;
    const float* Ab = in + (size_t)(i0 + ra) * N2 + (size_t)j * N + ca * 8;
    unsigned short* AsW0 = sm.s.A + ra * 64 + (((ca + 0) ^ (ra & 7)) * 8);
    unsigned short* AsW1 = sm.s.A + ra * 64 + (((ca + 1) ^ (ra & 7)) * 8);

    const unsigned short* Wj = wt + (size_t)j * N2 + (size_t)l0 * N;

    f32x4 acc[2][4];
#pragma unroll
    for (int m = 0; m < 2; ++m)
#pragma unroll
        for (int n = 0; n < 4; ++n) acc[m][n] = (f32x4){0.f, 0.f, 0.f, 0.f};

    float rsum = 0.f;

    float4 va[4];
    va[0] = *(const float4*)(Ab);
    va[1] = *(const float4*)(Ab + 4);
    va[2] = *(const float4*)(Ab + 8);
    va[3] = *(const float4*)(Ab + 12);

    // prologue: B(0) -> buf0, drain
    {
        unsigned short* B0 = sm.s.B[0];
#pragma unroll
        for (int op = 0; op < 4; ++op) {
            const int rr = wv * 32 + op * 8 + rb_off;
            const int sc = p8 ^ (rr & 7);
            gll16(Wj + (size_t)rr * N + sc * 8, B0 + (wv * 32 + op * 8) * 64);
        }
        asm volatile("s_waitcnt vmcnt(0)" ::: "memory");
    }

    unsigned short* Bc = sm.s.B[0];
    unsigned short* Bn = sm.s.B[1];

#pragma unroll
    for (int tt = 0; tt < 6; ++tt) {
        // stage A(tt) from regs (+rsum)
        rsum += (va[0].x + va[0].y + va[0].z + va[0].w) +
                (va[1].x + va[1].y + va[1].z + va[1].w) +
                (va[2].x + va[2].y + va[2].z + va[2].w) +
                (va[3].x + va[3].y + va[3].z + va[3].w);
        {
            uint4 a0, a1;
            a0.x = pk2(va[0].x, va[0].y); a0.y = pk2(va[0].z, va[0].w);
            a0.z = pk2(va[1].x, va[1].y); a0.w = pk2(va[1].z, va[1].w);
            a1.x = pk2(va[2].x, va[2].y); a1.y = pk2(va[2].z, va[2].w);
            a1.z = pk2(va[3].x, va[3].y); a1.w = pk2(va[3].z, va[3].w);
            *(uint4*)AsW0 = a0;
            *(uint4*)AsW1 = a1;
        }
        if (tt < 5) {
            const int kn = (tt + 1) * 64;
            // issue B(tt+1) glls FIRST (order pinned for the counted vmcnt)
#pragma unroll
            for (int op = 0; op < 4; ++op) {
                const int rr = wv * 32 + op * 8 + rb_off;
                const int sc = p8 ^ (rr & 7);
                gll16(Wj + (size_t)rr * N + kn + sc * 8, Bn + (wv * 32 + op * 8) * 64);
            }
            __builtin_amdgcn_sched_barrier(0);
            const float* An = Ab + kn;
            va[0] = *(const float4*)(An);
            va[1] = *(const float4*)(An + 4);
            va[2] = *(const float4*)(An + 8);
            va[3] = *(const float4*)(An + 12);
        }
        WAITL0;
        BAR;
        __builtin_amdgcn_s_setprio(1);
#pragma unroll
        for (int kk = 0; kk < 2; ++kk) {
            s16x8 af[2], bf[4];
#pragma unroll
            for (int m = 0; m < 2; ++m) {
                const int row = wr + m * 16 + fr;
                const int x   = (kk * 4 + fx) ^ (row & 7);
                af[m] = *(const s16x8*)(sm.s.A + row * 64 + x * 8);
            }
#pragma unroll
            for (int n = 0; n < 4; ++n) {
                const int row = wc + n * 16 + fr;
                const int x   = (kk * 4 + fx) ^ (row & 7);
                bf[n] = *(const s16x8*)(Bc + row * 64 + x * 8);
            }
#pragma unroll
            for (int m = 0; m < 2; ++m)
#pragma unroll
                for (int n = 0; n < 4; ++n)
                    acc[m][n] = __builtin_amdgcn_mfma_f32_16x16x32_bf16(
                        af[m], bf[n], acc[m][n], 0, 0, 0);
        }
        __builtin_amdgcn_s_setprio(0);
        if (tt < 5) {
            // retire the 4 B-glls; leave the 4 A-loads in flight
            asm volatile("s_waitcnt vmcnt(4)" ::: "memory");
        }
        BAR;   // release As + publish B(tt+1)
        unsigned short* tp = Bc; Bc = Bn; Bn = tp;
    }

    rsum += __shfl_xor(rsum, 1, 64);
    rsum += __shfl_xor(rsum, 2, 64);
    if (rs != nullptr && l0 == 0 && (t & 3) == 0)
        rs[(size_t)(i0 + ra) * N + j] = rsum;

    // epilogue: 64x128 bf16 tile in LDS, stream full lines
    __syncthreads();
    const int rq = fx * 4;
#pragma unroll
    for (int m = 0; m < 2; ++m)
#pragma unroll
        for (int n = 0; n < 4; ++n)
#pragma unroll
            for (int r = 0; r < 4; ++r)
                sm.C[(wr + m * 16 + rq + r) * 136 + wc + n * 16 + fr] =
                    f32_to_bf16(acc[m][n][r]);
    __syncthreads();
#pragma unroll
    for (int it = 0; it < 4; ++it) {
        const int cid = it * 256 + t;
        const int row = cid >> 4;
        const int c   = cid & 15;
        *(uint4*)(e + (size_t)(i0 + row) * N2 + (size_t)j * N + l0 + c * 8) =
            *(const uint4*)&sm.C[row * 136 + c * 8];
    }
}

// ---------------------------------------------------------------------------
// k_eT: et[i][l][m] = e[i][m][l]
// ---------------------------------------------------------------------------
__global__ __launch_bounds__(256) void k_eT(const unsigned short* __restrict__ e,
                                            unsigned short* __restrict__ et) {
    __shared__ unsigned short tile[64][68];
    const int m0 = blockIdx.x * 64, l0 = blockIdx.y * 64;
    const size_t ib = (size_t)blockIdx.z * N2;
    const int t  = threadIdx.x;
    const int c4 = (t & 15) * 4, r = t >> 4;
#pragma unroll
    for (int p = 0; p < 4; ++p) {
        ushort4 v = *(const ushort4*)(e + ib + (size_t)(m0 + r + 16 * p) * N + l0 + c4);
        tile[c4 + 0][r + 16 * p] = v.x;
        tile[c4 + 1][r + 16 * p] = v.y;
        tile[c4 + 2][r + 16 * p] = v.z;
        tile[c4 + 3][r + 16 * p] = v.w;
    }
    __syncthreads();
#pragma unroll
    for (int p = 0; p < 4; ++p) {
        const int lr = r + 16 * p;
        ushort4 v = *(const ushort4*)&tile[lr][c4];
        *(ushort4*)(et + ib + (size_t)(l0 + lr) * N + m0 + c4) = v;
    }
}

// ---------------------------------------------------------------------------
// k_attn: one wave per row (i,j); rs precomputed by k_e3
// ---------------------------------------------------------------------------
template <bool HAVE_RS>
__global__ __launch_bounds__(256) void k_attn(const float* __restrict__ in,
                                              const float* __restrict__ w,
                                              const float* __restrict__ rs,
                                              unsigned short* __restrict__ attn) {
    const int row  = blockIdx.x * 4 + (threadIdx.x >> 6);
    const int lane = threadIdx.x & 63;
    const int jr   = row % N;

    const float2* wp = (const float2*)(w + (size_t)row * N);

    float2 wv[3];
    float rs_in = 0.f, rs_w = 0.f;
#pragma unroll
    for (int c = 0; c < 3; ++c) {
        wv[c] = wp[lane + 64 * c];
        rs_w += wv[c].x + wv[c].y;
    }
    if (HAVE_RS) {
#pragma unroll
        for (int s = 1; s < 64; s <<= 1) rs_w += __shfl_xor(rs_w, s, 64);
        rs_in = rs[row];
    } else {
        const float2* ip = (const float2*)(in + (size_t)row * N);
#pragma unroll
        for (int c = 0; c < 3; ++c) {
            float2 iv = ip[lane + 64 * c];
            rs_in += iv.x + iv.y;
        }
#pragma unroll
        for (int s = 1; s < 64; s <<= 1) {
            rs_in += __shfl_xor(rs_in, s, 64);
            rs_w  += __shfl_xor(rs_w, s, 64);
        }
    }
    const float scale = rs_in / (0.5f + rs_w);

    float2 q[3];
    float mx = -INFINITY;
#pragma unroll
    for (int c = 0; c < 3; ++c) {
        const int l = (lane + 64 * c) * 2;
        q[c].x = (l     <= jr) ? scale * wv[c].x : -INFINITY;
        q[c].y = (l + 1 <= jr) ? scale * wv[c].y : -INFINITY;
        mx = fmaxf(mx, fmaxf(q[c].x, q[c].y));
    }
#pragma unroll
    for (int s = 1; s < 64; s <<= 1) mx = fmaxf(mx, __shfl_xor(mx, s, 64));

    float2 p[3];
    float sum = 0.f;
#pragma unroll
    for (int c = 0; c < 3; ++c) {
        const int l = (lane + 64 * c) * 2;
        p[c].x = (l     <= jr) ? exp2f((q[c].x - mx) * 1.44269504f) : 0.f;
        p[c].y = (l + 1 <= jr) ? exp2f((q[c].y - mx) * 1.44269504f) : 0.f;
        sum += p[c].x + p[c].y;
    }
#pragma unroll
    for (int s = 1; s < 64; s <<= 1) sum += __shfl_xor(sum, s, 64);
    const float inv = 1.f / sum;
    unsigned int* ap = (unsigned int*)(attn + (size_t)row * N);
#pragma unroll
    for (int c = 0; c < 3; ++c)
        ap[lane + 64 * c] = pk2(p[c].x * inv, p[c].y * inv);
}

// ---------------------------------------------------------------------------
// k_av3: per i: out[j0..j0+63, l0..l0+127] = attn[i] @ et[i]^T, K <= j0+64
// Same pipeline: A (attn, bf16) reg-staged; B (et) gll dbuf, vmcnt(2).
// ---------------------------------------------------------------------------
__global__ __launch_bounds__(256, 4) void k_av3(const unsigned short* __restrict__ attn,
                                                const unsigned short* __restrict__ et,
                                                float* __restrict__ out) {
    __shared__ union {
        struct { unsigned short A[64 * 64]; unsigned short B[2][128 * 64]; } s; // 40960 B
        float C[64 * 132];   // 33792 B
    } sm;

    const int lin = blockIdx.x;               // 6912 = 8 * 864
    const int swz = (lin & 7) * 864 + (lin >> 3);
    const int i   = swz / 18;
    const int sub = swz % 18;
    const int j0  = (sub / 3) * 64;
    const int l0  = (sub % 3) * 128;
    const int nt  = (j0 >> 6) + 1;            // K tiles: 1..6

    const int t = threadIdx.x, lane = t & 63, wv = t >> 6;
    const int fr = lane & 15, fx = lane >> 4;
    const int wr = (wv >> 1) * 32;
    const int wc = (wv & 1) * 64;
    const int rb_off = lane >> 3;
    const int p8     = lane & 7;

    // A path (reg-staged bf16): row ra, chunks ca, ca+1
    const int ra = t >> 2, ca = (t & 3) * 2;
    const unsigned short* Ab = attn + (size_t)i * N2 + (size_t)(j0 + ra) * N + ca * 8;
    unsigned short* AsW0 = sm.s.A + ra * 64 + (((ca + 0) ^ (ra & 7)) * 8);
    unsigned short* AsW1 = sm.s.A + ra * 64 + (((ca + 1) ^ (ra & 7)) * 8);

    const unsigned short* Bg = et + (size_t)i * N2 + (size_t)l0 * N;

    f32x4 acc[2][4];
#pragma unroll
    for (int m = 0; m < 2; ++m)
#pragma unroll
        for (int n = 0; n < 4; ++n) acc[m][n] = (f32x4){0.f, 0.f, 0.f, 0.f};

    uint4 va0 = *(const uint4*)(Ab);
    uint4 va1 = *(const uint4*)(Ab + 8);

    // prologue: B(0) -> buf0, drain
    {
        unsigned short* B0 = sm.s.B[0];
#pragma unroll
        for (int op = 0; op < 4; ++op) {
            const int rr = wv * 32 + op * 8 + rb_off;
            const int sc = p8 ^ (rr & 7);
            gll16(Bg + (size_t)rr * N + sc * 8, B0 + (wv * 32 + op * 8) * 64);
        }
        asm volatile("s_waitcnt vmcnt(0)" ::: "memory");
    }

    unsigned short* Bc = sm.s.B[0];
    unsigned short* Bn = sm.s.B[1];

    for (int tt = 0; tt < nt; ++tt) {
        *(uint4*)AsW0 = va0;
        *(uint4*)AsW1 = va1;
        if (tt + 1 < nt) {
            const int kn = (tt + 1) * 64;
#pragma unroll
            for (int op = 0; op < 4; ++op) {
                const int rr = wv * 32 + op * 8 + rb_off;
                const int sc = p8 ^ (rr & 7);
                gll16(Bg + (size_t)rr * N + kn + sc * 8, Bn + (wv * 32 + op * 8) * 64);
            }
            __builtin_amdgcn_sched_barrier(0);
            va0 = *(const uint4*)(Ab + kn);
            va1 = *(const uint4*)(Ab + kn + 8);
        }
        WAITL0;
        BAR;
        __builtin_amdgcn_s_setprio(1);
#pragma unroll
        for (int kk = 0; kk < 2; ++kk) {
            s16x8 af[2], bf[4];
#pragma unroll
            for (int m = 0; m < 2; ++m) {
                const int row = wr + m * 16 + fr;
                const int x   = (kk * 4 + fx) ^ (row & 7);
                af[m] = *(const s16x8*)(sm.s.A + row * 64 + x * 8);
            }
#pragma unroll
            for (int n = 0; n < 4; ++n) {
                const int row = wc + n * 16 + fr;
                const int x   = (kk * 4 + fx) ^ (row & 7);
                bf[n] = *(const s16x8*)(Bc + row * 64 + x * 8);
            }
#pragma unroll
            for (int m = 0; m < 2; ++m)
#pragma unroll
                for (int n = 0; n < 4; ++n)
                    acc[m][n] = __builtin_amdgcn_mfma_f32_16x16x32_bf16(
                        af[m], bf[n], acc[m][n], 0, 0, 0);
        }
        __builtin_amdgcn_s_setprio(0);
        if (tt + 1 < nt) {
            // retire the 4 B-glls; leave the 2 A-loads in flight
            asm volatile("s_waitcnt vmcnt(2)" ::: "memory");
        }
        BAR;
        unsigned short* tp = Bc; Bc = Bn; Bn = tp;
    }

    // epilogue: 64x128 fp32 tile in LDS, stream float4
    __syncthreads();
    const int rq = fx * 4;
#pragma unroll
    for (int m = 0; m < 2; ++m)
#pragma unroll
        for (int n = 0; n < 4; ++n)
#pragma unroll
            for (int r = 0; r < 4; ++r)
                sm.C[(wr + m * 16 + rq + r) * 132 + wc + n * 16 + fr] = acc[m][n][r];
    __syncthreads();
#pragma unroll
    for (int it = 0; it < 8; ++it) {
        const int cid = it * 256 + t;
        const int row = cid >> 5;
        const int c   = cid & 31;
        *(float4*)(out + (size_t)i * N2 + (size_t)(j0 + row) * N + l0 + c * 4) =
            *(const float4*)&sm.C[row * 132 + c * 4];
    }
}

extern "C" void kernel_launch(void* const* d_in, const int* in_sizes, int n_in,
                              void* d_out, int out_size, void* d_ws, size_t ws_size,
                              hipStream_t stream) {
    const float* in = (const float*)d_in[0];
    const float* w  = (const float*)d_in[1];
    float* out      = (float*)d_out;

    unsigned short* r0 = (unsigned short*)d_ws;       // wt -> et
    unsigned short* r1 = (unsigned short*)d_ws + N3;  // e  -> attn
    const bool have_rs = ws_size >= 2 * N3 * sizeof(unsigned short) + (size_t)N2 * sizeof(float);
    float* rs = have_rs ? (float*)((unsigned short*)d_ws + 2 * N3) : nullptr;

    kT<<<dim3(N2 / 64, N / 64), 256, 0, stream>>>(w, r0);
    k_e3<<<dim3(6912), 256, 0, stream>>>(in, r0, r1, rs);
    k_eT<<<dim3(6, 6, N), 256, 0, stream>>>(r1, r0);
    if (have_rs)
        k_attn<true><<<dim3(N2 / 4), 256, 0, stream>>>(in, w, rs, r1);
    else
        k_attn<false><<<dim3(N2 / 4), 256, 0, stream>>>(in, w, nullptr, r1);
    k_av3<<<dim3(6912), 256, 0, stream>>>(r1, r0, out);
}